// Round 1
// baseline (334.118 us; speedup 1.0000x reference)
//
#include <hip/hip_runtime.h>
#include <hip/hip_bf16.h>

typedef __attribute__((ext_vector_type(8))) short bf16x8;
typedef __attribute__((ext_vector_type(4))) float f32x4;

#define LOG2E 1.4426950408889634f

static __device__ __forceinline__ __hip_bfloat16 f2b(float f) {
    return __float2bfloat16(f);
}

// ---------------------------------------------------------------------------
// f32 -> bf16 elementwise convert (vectorized float4 in, 4x bf16 out)
// ---------------------------------------------------------------------------
__global__ __launch_bounds__(256) void k_f32_to_bf16(
    const float* __restrict__ in, __hip_bfloat16* __restrict__ out, int n4)
{
    int i = blockIdx.x * blockDim.x + threadIdx.x;
    int stride = gridDim.x * blockDim.x;
    for (; i < n4; i += stride) {
        float4 v = reinterpret_cast<const float4*>(in)[i];
        __hip_bfloat16* o = out + 4 * (size_t)i;
        o[0] = f2b(v.x); o[1] = f2b(v.y); o[2] = f2b(v.z); o[3] = f2b(v.w);
    }
}

// ---------------------------------------------------------------------------
// f32 [R][Cn] -> bf16 [Cn][R] tiled transpose (32x32 tile via LDS)
// ---------------------------------------------------------------------------
__global__ __launch_bounds__(256) void k_transpose_f32_bf16(
    const float* __restrict__ in, __hip_bfloat16* __restrict__ out, int R, int Cn)
{
    __shared__ float tile[32][33];
    const int c0 = blockIdx.x * 32, r0 = blockIdx.y * 32;
    const int tx = threadIdx.x & 31, ty = threadIdx.x >> 5; // ty in 0..7
#pragma unroll
    for (int i = 0; i < 32; i += 8)
        tile[ty + i][tx] = in[(size_t)(r0 + ty + i) * Cn + c0 + tx];
    __syncthreads();
#pragma unroll
    for (int i = 0; i < 32; i += 8)
        out[(size_t)(c0 + ty + i) * R + r0 + tx] = f2b(tile[tx][ty + i]);
}

// ---------------------------------------------------------------------------
// GEMM: C[M][N] = A[M][K] @ Bt[N][K]^T + bias
// m97 structure: 128x128 tile, BK=64, 4 waves (2x2 of 64x64), global_load_lds.
// EPI=0: qkv epilogue (scatter Q,K [BH][T][64], V transposed [BH][64][T],
//         Q pre-scaled by 1/8). EPI=1: f32 output + bias.
// ---------------------------------------------------------------------------
template <int EPI>
__global__ __launch_bounds__(256) void k_gemm_bt(
    const __hip_bfloat16* __restrict__ A,
    const __hip_bfloat16* __restrict__ Bt,
    const float* __restrict__ bias,
    int K, int Nn,
    float* __restrict__ outf,
    __hip_bfloat16* __restrict__ Qb,
    __hip_bfloat16* __restrict__ Kb,
    __hip_bfloat16* __restrict__ Vt)
{
    __shared__ __hip_bfloat16 As[128][64];
    __shared__ __hip_bfloat16 Bs[128][64];

    const int tid = threadIdx.x;
    const int lane = tid & 63;
    const int wid = tid >> 6;
    const int wm = wid >> 1, wn = wid & 1;
    const int m0 = blockIdx.y * 128, n0 = blockIdx.x * 128;
    const int l15 = lane & 15, lg = lane >> 4;

    f32x4 acc[4][4] = {};

    const int srow = tid >> 3;        // 0..31
    const int scol = (tid & 7) * 8;   // element offset in K

    for (int k0 = 0; k0 < K; k0 += 64) {
#pragma unroll
        for (int i = 0; i < 4; ++i) {
            int r = srow + 32 * i;
            __builtin_amdgcn_global_load_lds(
                (const __attribute__((address_space(1))) void*)(A + (size_t)(m0 + r) * K + k0 + scol),
                (__attribute__((address_space(3))) void*)(&As[r][scol]), 16, 0, 0);
        }
#pragma unroll
        for (int i = 0; i < 4; ++i) {
            int r = srow + 32 * i;
            __builtin_amdgcn_global_load_lds(
                (const __attribute__((address_space(1))) void*)(Bt + (size_t)(n0 + r) * K + k0 + scol),
                (__attribute__((address_space(3))) void*)(&Bs[r][scol]), 16, 0, 0);
        }
        __syncthreads();
#pragma unroll
        for (int c = 0; c < 2; ++c) {
            bf16x8 a[4], bb[4];
#pragma unroll
            for (int m = 0; m < 4; ++m)
                a[m] = *(const bf16x8*)&As[wm * 64 + m * 16 + l15][c * 32 + lg * 8];
#pragma unroll
            for (int n = 0; n < 4; ++n)
                bb[n] = *(const bf16x8*)&Bs[wn * 64 + n * 16 + l15][c * 32 + lg * 8];
#pragma unroll
            for (int m = 0; m < 4; ++m)
#pragma unroll
                for (int n = 0; n < 4; ++n)
                    acc[m][n] = __builtin_amdgcn_mfma_f32_16x16x32_bf16(a[m], bb[n], acc[m][n], 0, 0, 0);
        }
        __syncthreads();
    }

    // epilogue
#pragma unroll
    for (int m = 0; m < 4; ++m) {
        const int row = m0 + wm * 64 + m * 16 + lg * 4;
#pragma unroll
        for (int n = 0; n < 4; ++n) {
            const int col = n0 + wn * 64 + n * 16 + l15;
            const float bv = bias[col];
#pragma unroll
            for (int r = 0; r < 4; ++r) {
                float val = acc[m][n][r] + bv;
                const int rr = row + r;
                if (EPI == 0) {
                    const int sec = col >> 10, cw = col & 1023;
                    const int hh = cw >> 6, d = cw & 63;
                    const int bq = rr >> 11, t = rr & 2047;
                    const int bh = bq * 16 + hh;
                    if (sec == 0)
                        Qb[((size_t)bh * 2048 + t) * 64 + d] = f2b(val * 0.125f);
                    else if (sec == 1)
                        Kb[((size_t)bh * 2048 + t) * 64 + d] = f2b(val);
                    else
                        Vt[((size_t)bh * 64 + d) * 2048 + t] = f2b(val);
                } else {
                    outf[(size_t)rr * Nn + col] = val;
                }
            }
        }
    }
}

// ---------------------------------------------------------------------------
// Causal flash attention. Q,K: [BH][T][64] bf16 (Q pre-scaled by 1/8),
// Vt: [BH][64][T] bf16. Output att: [B*T][1024] bf16 ([b,t,h,d] flattened).
// 4 waves/block, each wave owns 16 q-rows; 32-key steps; K/V frags read
// directly from global (L2-resident per head).
// ---------------------------------------------------------------------------
__global__ __launch_bounds__(256) void k_attn(
    const __hip_bfloat16* __restrict__ Qb,
    const __hip_bfloat16* __restrict__ Kb,
    const __hip_bfloat16* __restrict__ Vt,
    __hip_bfloat16* __restrict__ att)
{
    __shared__ __hip_bfloat16 P_lds[4][16][32];
    const int tid = threadIdx.x, lane = tid & 63, wid = tid >> 6;
    const int bh = blockIdx.y;
    const int q0 = blockIdx.x * 64;
    const int qw = q0 + wid * 16;
    const int l15 = lane & 15, lg = lane >> 4;

    const __hip_bfloat16* Qbase = Qb + (size_t)bh * 2048 * 64;
    const __hip_bfloat16* Kbase = Kb + (size_t)bh * 2048 * 64;
    const __hip_bfloat16* Vbase = Vt + (size_t)bh * 64 * 2048;

    bf16x8 aq[2];
#pragma unroll
    for (int c = 0; c < 2; ++c)
        aq[c] = *(const bf16x8*)(Qbase + (size_t)(qw + l15) * 64 + c * 32 + lg * 8);

    f32x4 o[4] = {};
    float mrun[4], lrun[4];
#pragma unroll
    for (int r = 0; r < 4; ++r) { mrun[r] = -1e30f; lrun[r] = 0.f; }

    const int kend = q0 + 64;
    for (int ks = 0; ks < kend; ks += 32) {
        f32x4 s[2] = {};
#pragma unroll
        for (int f = 0; f < 2; ++f) {
            const __hip_bfloat16* kp = Kbase + (size_t)(ks + f * 16 + l15) * 64 + lg * 8;
#pragma unroll
            for (int c = 0; c < 2; ++c) {
                bf16x8 bk = *(const bf16x8*)(kp + c * 32);
                s[f] = __builtin_amdgcn_mfma_f32_16x16x32_bf16(aq[c], bk, s[f], 0, 0, 0);
            }
        }
        float alpha[4], pv0[4], pv1[4];
#pragma unroll
        for (int r = 0; r < 4; ++r) {
            const int qrow = qw + lg * 4 + r;
            float v0 = (ks + l15 <= qrow) ? s[0][r] : -1e30f;
            float v1 = (ks + 16 + l15 <= qrow) ? s[1][r] : -1e30f;
            float mx = fmaxf(v0, v1);
#pragma unroll
            for (int off = 1; off < 16; off <<= 1)
                mx = fmaxf(mx, __shfl_xor(mx, off, 64));
            const float mnew = fmaxf(mrun[r], mx);
            alpha[r] = __expf(mrun[r] - mnew);
            const float p0 = __expf(v0 - mnew);
            const float p1 = __expf(v1 - mnew);
            float rs = p0 + p1;
#pragma unroll
            for (int off = 1; off < 16; off <<= 1)
                rs += __shfl_xor(rs, off, 64);
            lrun[r] = lrun[r] * alpha[r] + rs;
            mrun[r] = mnew;
            pv0[r] = p0; pv1[r] = p1;
        }
#pragma unroll
        for (int dc = 0; dc < 4; ++dc)
#pragma unroll
            for (int r = 0; r < 4; ++r)
                o[dc][r] *= alpha[r];
        // stage P to LDS (per-wave region) to reach MFMA A-layout
        __syncthreads();
#pragma unroll
        for (int r = 0; r < 4; ++r) {
            P_lds[wid][lg * 4 + r][l15]      = f2b(pv0[r]);
            P_lds[wid][lg * 4 + r][16 + l15] = f2b(pv1[r]);
        }
        __syncthreads();
        const bf16x8 ap = *(const bf16x8*)&P_lds[wid][l15][lg * 8];
#pragma unroll
        for (int dc = 0; dc < 4; ++dc) {
            bf16x8 bv = *(const bf16x8*)(Vbase + (size_t)(dc * 16 + l15) * 2048 + ks + lg * 8);
            o[dc] = __builtin_amdgcn_mfma_f32_16x16x32_bf16(ap, bv, o[dc], 0, 0, 0);
        }
    }

    const int bq = bh >> 4, hh = bh & 15;
#pragma unroll
    for (int dc = 0; dc < 4; ++dc)
#pragma unroll
        for (int r = 0; r < 4; ++r) {
            const int qrow = qw + lg * 4 + r;
            const float val = o[dc][r] / lrun[r];
            att[((size_t)(bq * 2048 + qrow)) * 1024 + hh * 64 + dc * 16 + l15] = f2b(val);
        }
}

// ---------------------------------------------------------------------------
extern "C" void kernel_launch(void* const* d_in, const int* in_sizes, int n_in,
                              void* d_out, int out_size, void* d_ws, size_t ws_size,
                              hipStream_t stream)
{
    const float* x    = (const float*)d_in[0];   // [2,2048,1024]
    const float* Wqkv = (const float*)d_in[1];   // [1024,3072]
    const float* bqkv = (const float*)d_in[2];   // [3072]
    const float* Wo   = (const float*)d_in[3];   // [1024,1024]
    const float* bo   = (const float*)d_in[4];   // [1024]
    float* out = (float*)d_out;                  // [2,2048,1024]

    char* ws = (char*)d_ws;
    const size_t MB = 1024 * 1024;
    __hip_bfloat16* xb    = (__hip_bfloat16*)(ws);            //  8 MB [4096][1024]
    __hip_bfloat16* WqkvT = (__hip_bfloat16*)(ws + 8 * MB);   //  6 MB [3072][1024]
    __hip_bfloat16* WoT   = (__hip_bfloat16*)(ws + 14 * MB);  //  2 MB [1024][1024]
    __hip_bfloat16* Qb    = (__hip_bfloat16*)(ws + 16 * MB);  //  8 MB [32][2048][64]
    __hip_bfloat16* Kb    = (__hip_bfloat16*)(ws + 24 * MB);  //  8 MB [32][2048][64]
    __hip_bfloat16* Vt    = (__hip_bfloat16*)(ws + 32 * MB);  //  8 MB [32][64][2048]
    __hip_bfloat16* att   = (__hip_bfloat16*)(ws + 40 * MB);  //  8 MB [4096][1024]

    k_f32_to_bf16<<<2048, 256, 0, stream>>>(x, xb, 4096 * 1024 / 4);
    k_transpose_f32_bf16<<<dim3(96, 32), 256, 0, stream>>>(Wqkv, WqkvT, 1024, 3072);
    k_transpose_f32_bf16<<<dim3(32, 32), 256, 0, stream>>>(Wo, WoT, 1024, 1024);

    k_gemm_bt<0><<<dim3(24, 32), 256, 0, stream>>>(
        xb, WqkvT, bqkv, 1024, 3072, nullptr, Qb, Kb, Vt);

    k_attn<<<dim3(32, 32), 256, 0, stream>>>(Qb, Kb, Vt, att);

    k_gemm_bt<1><<<dim3(8, 32), 256, 0, stream>>>(
        att, WoT, bo, 1024, 1024, out, nullptr, nullptr, nullptr);
}

// Round 2
// 223.341 us; speedup vs baseline: 1.4960x; 1.4960x over previous
//
#include <hip/hip_runtime.h>
#include <hip/hip_bf16.h>

typedef __attribute__((ext_vector_type(8))) short bf16x8;
typedef __attribute__((ext_vector_type(4))) float f32x4;

static __device__ __forceinline__ __hip_bfloat16 f2b(float f) {
    return __float2bfloat16(f);
}

// ---------------------------------------------------------------------------
// f32 -> bf16 elementwise convert (vectorized float4 in, 4x bf16 out)
// ---------------------------------------------------------------------------
__global__ __launch_bounds__(256) void k_f32_to_bf16(
    const float* __restrict__ in, __hip_bfloat16* __restrict__ out, int n4)
{
    int i = blockIdx.x * blockDim.x + threadIdx.x;
    int stride = gridDim.x * blockDim.x;
    for (; i < n4; i += stride) {
        float4 v = reinterpret_cast<const float4*>(in)[i];
        __hip_bfloat16* o = out + 4 * (size_t)i;
        o[0] = f2b(v.x); o[1] = f2b(v.y); o[2] = f2b(v.z); o[3] = f2b(v.w);
    }
}

// ---------------------------------------------------------------------------
// f32 [R][Cn] -> bf16 [Cn][R] tiled transpose (32x32 tile via LDS)
// ---------------------------------------------------------------------------
__global__ __launch_bounds__(256) void k_transpose_f32_bf16(
    const float* __restrict__ in, __hip_bfloat16* __restrict__ out, int R, int Cn)
{
    __shared__ float tile[32][33];
    const int c0 = blockIdx.x * 32, r0 = blockIdx.y * 32;
    const int tx = threadIdx.x & 31, ty = threadIdx.x >> 5; // ty in 0..7
#pragma unroll
    for (int i = 0; i < 32; i += 8)
        tile[ty + i][tx] = in[(size_t)(r0 + ty + i) * Cn + c0 + tx];
    __syncthreads();
#pragma unroll
    for (int i = 0; i < 32; i += 8)
        out[(size_t)(c0 + ty + i) * R + r0 + tx] = f2b(tile[tx][ty + i]);
}

// ---------------------------------------------------------------------------
// GEMM: C[M][N] = A[M][K] @ Bt[N][K]^T + bias
// m97 structure: 128x128 tile, BK=64, 4 waves (2x2 of 64x64), global_load_lds.
// EPI=0: qkv epilogue (scatter Q,K [BH][T][64], V transposed [BH][64][T],
//         Q pre-scaled by 1/8). EPI=1: f32 output + bias.
// ---------------------------------------------------------------------------
template <int EPI>
__global__ __launch_bounds__(256) void k_gemm_bt(
    const __hip_bfloat16* __restrict__ A,
    const __hip_bfloat16* __restrict__ Bt,
    const float* __restrict__ bias,
    int K, int Nn,
    float* __restrict__ outf,
    __hip_bfloat16* __restrict__ Qb,
    __hip_bfloat16* __restrict__ Kb,
    __hip_bfloat16* __restrict__ Vt)
{
    __shared__ __hip_bfloat16 As[128][64];
    __shared__ __hip_bfloat16 Bs[128][64];

    const int tid = threadIdx.x;
    const int lane = tid & 63;
    const int wid = tid >> 6;
    const int wm = wid >> 1, wn = wid & 1;
    const int m0 = blockIdx.y * 128, n0 = blockIdx.x * 128;
    const int l15 = lane & 15, lg = lane >> 4;

    f32x4 acc[4][4] = {};

    const int srow = tid >> 3;        // 0..31
    const int scol = (tid & 7) * 8;   // element offset in K

    for (int k0 = 0; k0 < K; k0 += 64) {
#pragma unroll
        for (int i = 0; i < 4; ++i) {
            int r = srow + 32 * i;
            __builtin_amdgcn_global_load_lds(
                (const __attribute__((address_space(1))) void*)(A + (size_t)(m0 + r) * K + k0 + scol),
                (__attribute__((address_space(3))) void*)(&As[r][scol]), 16, 0, 0);
        }
#pragma unroll
        for (int i = 0; i < 4; ++i) {
            int r = srow + 32 * i;
            __builtin_amdgcn_global_load_lds(
                (const __attribute__((address_space(1))) void*)(Bt + (size_t)(n0 + r) * K + k0 + scol),
                (__attribute__((address_space(3))) void*)(&Bs[r][scol]), 16, 0, 0);
        }
        __syncthreads();
#pragma unroll
        for (int c = 0; c < 2; ++c) {
            bf16x8 a[4], bb[4];
#pragma unroll
            for (int m = 0; m < 4; ++m)
                a[m] = *(const bf16x8*)&As[wm * 64 + m * 16 + l15][c * 32 + lg * 8];
#pragma unroll
            for (int n = 0; n < 4; ++n)
                bb[n] = *(const bf16x8*)&Bs[wn * 64 + n * 16 + l15][c * 32 + lg * 8];
#pragma unroll
            for (int m = 0; m < 4; ++m)
#pragma unroll
                for (int n = 0; n < 4; ++n)
                    acc[m][n] = __builtin_amdgcn_mfma_f32_16x16x32_bf16(a[m], bb[n], acc[m][n], 0, 0, 0);
        }
        __syncthreads();
    }

    // epilogue
#pragma unroll
    for (int m = 0; m < 4; ++m) {
        const int row = m0 + wm * 64 + m * 16 + lg * 4;
#pragma unroll
        for (int n = 0; n < 4; ++n) {
            const int col = n0 + wn * 64 + n * 16 + l15;
            const float bv = bias[col];
#pragma unroll
            for (int r = 0; r < 4; ++r) {
                float val = acc[m][n][r] + bv;
                const int rr = row + r;
                if (EPI == 0) {
                    const int sec = col >> 10, cw = col & 1023;
                    const int hh = cw >> 6, d = cw & 63;
                    const int bq = rr >> 11, t = rr & 2047;
                    const int bh = bq * 16 + hh;
                    if (sec == 0)
                        Qb[((size_t)bh * 2048 + t) * 64 + d] = f2b(val * 0.125f);
                    else if (sec == 1)
                        Kb[((size_t)bh * 2048 + t) * 64 + d] = f2b(val);
                    else
                        Vt[((size_t)bh * 64 + d) * 2048 + t] = f2b(val);
                } else {
                    outf[(size_t)rr * Nn + col] = val;
                }
            }
        }
    }
}

// ---------------------------------------------------------------------------
// Causal flash attention v2.
// Q,K: [BH][T][64] bf16 (Q pre-scaled by 1/8), Vt: [BH][64][T] bf16.
// Output att: [B*T][1024] bf16.
// 4 waves/block, 32 q-rows/wave (block = 128 q-rows), 64-key steps.
// No block barriers (per-wave LDS P staging, XOR-swizzled).
// XCD-aware swizzle: each head's 16 q-blocks land on one XCD.
// ---------------------------------------------------------------------------
#define PSWZ(row, col) (((row) * 64) + ((col) ^ (((row) & 7) << 3)))

__global__ __launch_bounds__(256) void k_attn(
    const __hip_bfloat16* __restrict__ Qb,
    const __hip_bfloat16* __restrict__ Kb,
    const __hip_bfloat16* __restrict__ Vt,
    __hip_bfloat16* __restrict__ att)
{
    __shared__ __hip_bfloat16 P_lds[4][2][16 * 64];
    const int tid = threadIdx.x, lane = tid & 63, wid = tid >> 6;
    // XCD-aware swizzle: 512 blocks, linear id % 8 = XCD (round-robin).
    // Give each XCD 4 whole heads (4 x 512KB = 2MB <= 4MB L2/XCD).
    const int lid = blockIdx.y * gridDim.x + blockIdx.x;
    const int xcd = lid & 7, slot = lid >> 3;      // slot 0..63
    const int bh = xcd * 4 + (slot & 3);           // 0..31
    const int q0 = (slot >> 2) * 128;              // 0..1920
    const int qw = q0 + wid * 32;
    const int l15 = lane & 15, lg = lane >> 4;

    const __hip_bfloat16* Qbase = Qb + (size_t)bh * 2048 * 64;
    const __hip_bfloat16* Kbase = Kb + (size_t)bh * 2048 * 64;
    const __hip_bfloat16* Vbase = Vt + (size_t)bh * 64 * 2048;

    bf16x8 aq[2][2];
#pragma unroll
    for (int qf = 0; qf < 2; ++qf)
#pragma unroll
        for (int c = 0; c < 2; ++c)
            aq[qf][c] = *(const bf16x8*)(Qbase + (size_t)(qw + qf * 16 + l15) * 64 + c * 32 + lg * 8);

    f32x4 o[2][4] = {};
    float mrun[2][4], lrun[2][4];
#pragma unroll
    for (int qf = 0; qf < 2; ++qf)
#pragma unroll
        for (int r = 0; r < 4; ++r) { mrun[qf][r] = -1e30f; lrun[qf][r] = 0.f; }

    const int kmax = qw + 31;   // last valid key for this wave
    for (int ks = 0; ks <= kmax; ks += 64) {
        // ---- QK^T over up to 64 keys (skip fully-masked 16-key fragments) ----
        f32x4 s[2][4] = {};
#pragma unroll
        for (int kf = 0; kf < 4; ++kf) {
            if (ks + kf * 16 <= kmax) {   // wave-uniform
                const __hip_bfloat16* kp = Kbase + (size_t)(ks + kf * 16 + l15) * 64 + lg * 8;
                bf16x8 bk0 = *(const bf16x8*)(kp);
                bf16x8 bk1 = *(const bf16x8*)(kp + 32);
#pragma unroll
                for (int qf = 0; qf < 2; ++qf) {
                    s[qf][kf] = __builtin_amdgcn_mfma_f32_16x16x32_bf16(aq[qf][0], bk0, s[qf][kf], 0, 0, 0);
                    s[qf][kf] = __builtin_amdgcn_mfma_f32_16x16x32_bf16(aq[qf][1], bk1, s[qf][kf], 0, 0, 0);
                }
            }
        }
        // ---- prefetch V fragments (hide latency under softmax VALU) ----
        bf16x8 bv[4][2];
#pragma unroll
        for (int c2 = 0; c2 < 2; ++c2)
            if (ks + c2 * 32 <= kmax)
#pragma unroll
                for (int dc = 0; dc < 4; ++dc)
                    bv[dc][c2] = *(const bf16x8*)(Vbase + (size_t)(dc * 16 + l15) * 2048 + ks + c2 * 32 + lg * 8);

        // ---- online softmax (per lane: 8 q-rows x 4 key-frag values) ----
        float alph[2][4];
#pragma unroll
        for (int qf = 0; qf < 2; ++qf) {
            __hip_bfloat16* Pw = &P_lds[wid][qf][0];
#pragma unroll
            for (int r = 0; r < 4; ++r) {
                const int q = qw + qf * 16 + lg * 4 + r;
                float v0 = (ks + l15 <= q)      ? s[qf][0][r] : -1e30f;
                float v1 = (ks + 16 + l15 <= q) ? s[qf][1][r] : -1e30f;
                float v2 = (ks + 32 + l15 <= q) ? s[qf][2][r] : -1e30f;
                float v3 = (ks + 48 + l15 <= q) ? s[qf][3][r] : -1e30f;
                float mx = fmaxf(fmaxf(v0, v1), fmaxf(v2, v3));
#pragma unroll
                for (int off = 1; off < 16; off <<= 1)
                    mx = fmaxf(mx, __shfl_xor(mx, off, 64));
                const float mold = mrun[qf][r];
                const float mnew = fmaxf(mold, mx);
                alph[qf][r] = __expf(mold - mnew);
                const float p0 = __expf(v0 - mnew);
                const float p1 = __expf(v1 - mnew);
                const float p2 = __expf(v2 - mnew);
                const float p3 = __expf(v3 - mnew);
                float rs = (p0 + p1) + (p2 + p3);
#pragma unroll
                for (int off = 1; off < 16; off <<= 1)
                    rs += __shfl_xor(rs, off, 64);
                lrun[qf][r] = lrun[qf][r] * alph[qf][r] + rs;
                mrun[qf][r] = mnew;
                const int row = lg * 4 + r;
                Pw[PSWZ(row, l15)]      = f2b(p0);
                Pw[PSWZ(row, 16 + l15)] = f2b(p1);
                Pw[PSWZ(row, 32 + l15)] = f2b(p2);
                Pw[PSWZ(row, 48 + l15)] = f2b(p3);
            }
        }
        // ---- rescale O ----
#pragma unroll
        for (int qf = 0; qf < 2; ++qf)
#pragma unroll
            for (int dc = 0; dc < 4; ++dc)
#pragma unroll
                for (int r = 0; r < 4; ++r)
                    o[qf][dc][r] *= alph[qf][r];
        // ---- PV (skip fully-masked 32-key halves) ----
#pragma unroll
        for (int c2 = 0; c2 < 2; ++c2) {
            if (ks + c2 * 32 <= kmax) {
#pragma unroll
                for (int qf = 0; qf < 2; ++qf) {
                    const bf16x8 ap = *(const bf16x8*)&P_lds[wid][qf][PSWZ(l15, c2 * 32 + lg * 8)];
#pragma unroll
                    for (int dc = 0; dc < 4; ++dc)
                        o[qf][dc] = __builtin_amdgcn_mfma_f32_16x16x32_bf16(ap, bv[dc][c2], o[qf][dc], 0, 0, 0);
                }
            }
        }
    }

    const int bq = bh >> 4, hh = bh & 15;
#pragma unroll
    for (int qf = 0; qf < 2; ++qf)
#pragma unroll
        for (int dc = 0; dc < 4; ++dc)
#pragma unroll
            for (int r = 0; r < 4; ++r) {
                const int qrow = qw + qf * 16 + lg * 4 + r;
                const float val = o[qf][dc][r] / lrun[qf][r];
                att[((size_t)(bq * 2048 + qrow)) * 1024 + hh * 64 + dc * 16 + l15] = f2b(val);
            }
}

// ---------------------------------------------------------------------------
extern "C" void kernel_launch(void* const* d_in, const int* in_sizes, int n_in,
                              void* d_out, int out_size, void* d_ws, size_t ws_size,
                              hipStream_t stream)
{
    const float* x    = (const float*)d_in[0];   // [2,2048,1024]
    const float* Wqkv = (const float*)d_in[1];   // [1024,3072]
    const float* bqkv = (const float*)d_in[2];   // [3072]
    const float* Wo   = (const float*)d_in[3];   // [1024,1024]
    const float* bo   = (const float*)d_in[4];   // [1024]
    float* out = (float*)d_out;                  // [2,2048,1024]

    char* ws = (char*)d_ws;
    const size_t MB = 1024 * 1024;
    __hip_bfloat16* xb    = (__hip_bfloat16*)(ws);            //  8 MB [4096][1024]
    __hip_bfloat16* WqkvT = (__hip_bfloat16*)(ws + 8 * MB);   //  6 MB [3072][1024]
    __hip_bfloat16* WoT   = (__hip_bfloat16*)(ws + 14 * MB);  //  2 MB [1024][1024]
    __hip_bfloat16* Qb    = (__hip_bfloat16*)(ws + 16 * MB);  //  8 MB [32][2048][64]
    __hip_bfloat16* Kb    = (__hip_bfloat16*)(ws + 24 * MB);  //  8 MB [32][2048][64]
    __hip_bfloat16* Vt    = (__hip_bfloat16*)(ws + 32 * MB);  //  8 MB [32][64][2048]
    __hip_bfloat16* att   = (__hip_bfloat16*)(ws + 40 * MB);  //  8 MB [4096][1024]

    k_f32_to_bf16<<<2048, 256, 0, stream>>>(x, xb, 4096 * 1024 / 4);
    k_transpose_f32_bf16<<<dim3(96, 32), 256, 0, stream>>>(Wqkv, WqkvT, 1024, 3072);
    k_transpose_f32_bf16<<<dim3(32, 32), 256, 0, stream>>>(Wo, WoT, 1024, 1024);

    k_gemm_bt<0><<<dim3(24, 32), 256, 0, stream>>>(
        xb, WqkvT, bqkv, 1024, 3072, nullptr, Qb, Kb, Vt);

    k_attn<<<dim3(16, 32), 256, 0, stream>>>(Qb, Kb, Vt, att);

    k_gemm_bt<1><<<dim3(8, 32), 256, 0, stream>>>(
        att, WoT, bo, 1024, 1024, out, nullptr, nullptr, nullptr);
}

// Round 3
// 187.833 us; speedup vs baseline: 1.7788x; 1.1890x over previous
//
#include <hip/hip_runtime.h>
#include <hip/hip_bf16.h>

typedef __attribute__((ext_vector_type(8))) short bf16x8;
typedef __attribute__((ext_vector_type(4))) short bf16x4;
typedef __attribute__((ext_vector_type(4))) float f32x4;

static __device__ __forceinline__ __hip_bfloat16 f2b(float f) {
    return __float2bfloat16(f);
}
static __device__ __forceinline__ unsigned pack2(float a, float b) {
    unsigned ua = (unsigned)__bfloat16_as_ushort(__float2bfloat16(a));
    unsigned ub = (unsigned)__bfloat16_as_ushort(__float2bfloat16(b));
    return ua | (ub << 16);
}

// ---------------------------------------------------------------------------
// f32 -> bf16 elementwise convert
// ---------------------------------------------------------------------------
__global__ __launch_bounds__(256) void k_f32_to_bf16(
    const float* __restrict__ in, __hip_bfloat16* __restrict__ out, int n4)
{
    int i = blockIdx.x * blockDim.x + threadIdx.x;
    int stride = gridDim.x * blockDim.x;
    for (; i < n4; i += stride) {
        float4 v = reinterpret_cast<const float4*>(in)[i];
        __hip_bfloat16* o = out + 4 * (size_t)i;
        o[0] = f2b(v.x); o[1] = f2b(v.y); o[2] = f2b(v.z); o[3] = f2b(v.w);
    }
}

// ---------------------------------------------------------------------------
// f32 [R][Cn] -> bf16 [Cn][R] tiled transpose
// ---------------------------------------------------------------------------
__global__ __launch_bounds__(256) void k_transpose_f32_bf16(
    const float* __restrict__ in, __hip_bfloat16* __restrict__ out, int R, int Cn)
{
    __shared__ float tile[32][33];
    const int c0 = blockIdx.x * 32, r0 = blockIdx.y * 32;
    const int tx = threadIdx.x & 31, ty = threadIdx.x >> 5;
#pragma unroll
    for (int i = 0; i < 32; i += 8)
        tile[ty + i][tx] = in[(size_t)(r0 + ty + i) * Cn + c0 + tx];
    __syncthreads();
#pragma unroll
    for (int i = 0; i < 32; i += 8)
        out[(size_t)(c0 + ty + i) * R + r0 + tx] = f2b(tile[tx][ty + i]);
}

// ---------------------------------------------------------------------------
// GEMM: C[M][N] = A[M][K] @ Bt[N][K]^T + bias  (m97 structure)
// ---------------------------------------------------------------------------
template <int EPI>
__global__ __launch_bounds__(256) void k_gemm_bt(
    const __hip_bfloat16* __restrict__ A,
    const __hip_bfloat16* __restrict__ Bt,
    const float* __restrict__ bias,
    int K, int Nn,
    float* __restrict__ outf,
    __hip_bfloat16* __restrict__ Qb,
    __hip_bfloat16* __restrict__ Kb,
    __hip_bfloat16* __restrict__ Vt)
{
    __shared__ __hip_bfloat16 As[128][64];
    __shared__ __hip_bfloat16 Bs[128][64];

    const int tid = threadIdx.x;
    const int lane = tid & 63;
    const int wid = tid >> 6;
    const int wm = wid >> 1, wn = wid & 1;
    const int m0 = blockIdx.y * 128, n0 = blockIdx.x * 128;
    const int l15 = lane & 15, lg = lane >> 4;

    f32x4 acc[4][4] = {};

    const int srow = tid >> 3;
    const int scol = (tid & 7) * 8;

    for (int k0 = 0; k0 < K; k0 += 64) {
#pragma unroll
        for (int i = 0; i < 4; ++i) {
            int r = srow + 32 * i;
            __builtin_amdgcn_global_load_lds(
                (const __attribute__((address_space(1))) void*)(A + (size_t)(m0 + r) * K + k0 + scol),
                (__attribute__((address_space(3))) void*)(&As[r][scol]), 16, 0, 0);
        }
#pragma unroll
        for (int i = 0; i < 4; ++i) {
            int r = srow + 32 * i;
            __builtin_amdgcn_global_load_lds(
                (const __attribute__((address_space(1))) void*)(Bt + (size_t)(n0 + r) * K + k0 + scol),
                (__attribute__((address_space(3))) void*)(&Bs[r][scol]), 16, 0, 0);
        }
        __syncthreads();
#pragma unroll
        for (int c = 0; c < 2; ++c) {
            bf16x8 a[4], bb[4];
#pragma unroll
            for (int m = 0; m < 4; ++m)
                a[m] = *(const bf16x8*)&As[wm * 64 + m * 16 + l15][c * 32 + lg * 8];
#pragma unroll
            for (int n = 0; n < 4; ++n)
                bb[n] = *(const bf16x8*)&Bs[wn * 64 + n * 16 + l15][c * 32 + lg * 8];
#pragma unroll
            for (int m = 0; m < 4; ++m)
#pragma unroll
                for (int n = 0; n < 4; ++n)
                    acc[m][n] = __builtin_amdgcn_mfma_f32_16x16x32_bf16(a[m], bb[n], acc[m][n], 0, 0, 0);
        }
        __syncthreads();
    }

#pragma unroll
    for (int m = 0; m < 4; ++m) {
        const int row = m0 + wm * 64 + m * 16 + lg * 4;
#pragma unroll
        for (int n = 0; n < 4; ++n) {
            const int col = n0 + wn * 64 + n * 16 + l15;
            const float bv = bias[col];
#pragma unroll
            for (int r = 0; r < 4; ++r) {
                float val = acc[m][n][r] + bv;
                const int rr = row + r;
                if (EPI == 0) {
                    const int sec = col >> 10, cw = col & 1023;
                    const int hh = cw >> 6, d = cw & 63;
                    const int bq = rr >> 11, t = rr & 2047;
                    const int bh = bq * 16 + hh;
                    if (sec == 0)
                        Qb[((size_t)bh * 2048 + t) * 64 + d] = f2b(val * 0.125f);
                    else if (sec == 1)
                        Kb[((size_t)bh * 2048 + t) * 64 + d] = f2b(val);
                    else
                        Vt[((size_t)bh * 64 + d) * 2048 + t] = f2b(val);
                } else {
                    outf[(size_t)rr * Nn + col] = val;
                }
            }
        }
    }
}

// ---------------------------------------------------------------------------
// Causal flash attention v3 — swapped-operand MFMA so softmax is lane-local.
// Q,K: [BH][T][64] bf16 (Q pre-scaled by 1/8), Vt: [BH][64][T] bf16.
// Output att: [B*T][1024] bf16.
// 4 waves/block, 32 q-rows/wave, 64-key steps, no block barriers.
// S = mfma(K,Q):  row = key (in-lane lg*4+r), col = q (l15)
// O = mfma(Vt,P): row = d   (in-lane lg*4+r), col = q (l15)
// Heavy-first dispatch: first 256 blocks get q-tiles 8..15.
// ---------------------------------------------------------------------------
__global__ __launch_bounds__(256) void k_attn(
    const __hip_bfloat16* __restrict__ Qb,
    const __hip_bfloat16* __restrict__ Kb,
    const __hip_bfloat16* __restrict__ Vt,
    __hip_bfloat16* __restrict__ att)
{
    __shared__ __hip_bfloat16 P_lds[4][2][16 * 64];
    const int tid = threadIdx.x, lane = tid & 63, wid = tid >> 6;
    const int lid = blockIdx.x;
    const int xcd = lid & 7, j = lid >> 3;      // per-XCD slot 0..63
    const int jj = j >> 2;                       // 0..15
    const int tile = (jj < 8) ? (15 - jj) : (jj - 8);   // heavy tiles first
    const int bh = xcd * 4 + (j & 3);            // 4 heads per XCD
    const int q0 = tile * 128;
    const int qw = q0 + wid * 32;
    const int l15 = lane & 15, lg = lane >> 4;
    const int swz = (l15 & 7) << 3;

    const __hip_bfloat16* Qbase = Qb + (size_t)bh * 2048 * 64;
    const __hip_bfloat16* Kbase = Kb + (size_t)bh * 2048 * 64;
    const __hip_bfloat16* Vbase = Vt + (size_t)bh * 64 * 2048;

    // Q as B-operand: lane l15 = q column, elems over d
    bf16x8 aq[2][2];
#pragma unroll
    for (int qf = 0; qf < 2; ++qf)
#pragma unroll
        for (int c = 0; c < 2; ++c)
            aq[qf][c] = *(const bf16x8*)(Qbase + (size_t)(qw + qf * 16 + l15) * 64 + c * 32 + lg * 8);

    f32x4 o[2][4] = {};
    float mrun[2] = {-1e30f, -1e30f}, lrun[2] = {0.f, 0.f};

    const int kmax = qw + 31;
    for (int ks = 0; ks <= kmax; ks += 64) {
        const bool hi = (ks + 32 <= kmax);
        // K as A-operand: lane l15 = key row, elems over d
        bf16x8 bk[4][2];
#pragma unroll
        for (int kf = 0; kf < 4; ++kf) {
            if (kf < 2 || hi) {
                const __hip_bfloat16* kp = Kbase + (size_t)(ks + kf * 16 + l15) * 64 + lg * 8;
                bk[kf][0] = *(const bf16x8*)(kp);
                bk[kf][1] = *(const bf16x8*)(kp + 32);
            }
        }
        // V^T as A-operand: lane l15 = d row, elems over key
        bf16x8 bv[4][2];
#pragma unroll
        for (int c2 = 0; c2 < 2; ++c2)
            if (c2 == 0 || hi)
#pragma unroll
                for (int dc = 0; dc < 4; ++dc)
                    bv[dc][c2] = *(const bf16x8*)(Vbase + (size_t)(dc * 16 + l15) * 2048 + ks + c2 * 32 + lg * 8);

#pragma unroll
        for (int qf = 0; qf < 2; ++qf) {
            const int qlo = qw + qf * 16;
            if (ks > qlo + 15) continue;          // fully masked for this qf
            f32x4 s[4] = {};
#pragma unroll
            for (int kf = 0; kf < 4; ++kf) {
                if (ks + kf * 16 <= qlo + 15) {
                    s[kf] = __builtin_amdgcn_mfma_f32_16x16x32_bf16(bk[kf][0], aq[qf][0], s[kf], 0, 0, 0);
                    s[kf] = __builtin_amdgcn_mfma_f32_16x16x32_bf16(bk[kf][1], aq[qf][1], s[kf], 0, 0, 0);
                }
            }
            const int qv = qlo + l15;             // this lane's q row
            float p[4][4];
            if (ks + 63 <= qlo) {                 // fully unmasked fast path
#pragma unroll
                for (int kf = 0; kf < 4; ++kf)
#pragma unroll
                    for (int r = 0; r < 4; ++r) p[kf][r] = s[kf][r];
            } else {
                const int kb = ks + lg * 4;
#pragma unroll
                for (int kf = 0; kf < 4; ++kf)
#pragma unroll
                    for (int r = 0; r < 4; ++r)
                        p[kf][r] = (kb + kf * 16 + r <= qv) ? s[kf][r] : -1e30f;
            }
            // lane-local row max over 16 values + 2 cross-group shfls
            float mx = fmaxf(fmaxf(fmaxf(p[0][0], p[0][1]), fmaxf(p[0][2], p[0][3])),
                             fmaxf(fmaxf(p[1][0], p[1][1]), fmaxf(p[1][2], p[1][3])));
            mx = fmaxf(mx, fmaxf(fmaxf(fmaxf(p[2][0], p[2][1]), fmaxf(p[2][2], p[2][3])),
                                 fmaxf(fmaxf(p[3][0], p[3][1]), fmaxf(p[3][2], p[3][3]))));
            mx = fmaxf(mx, __shfl_xor(mx, 16));
            mx = fmaxf(mx, __shfl_xor(mx, 32));
            const float mnew = fmaxf(mrun[qf], mx);
            const float al = __expf(mrun[qf] - mnew);
            mrun[qf] = mnew;
            float rs = 0.f;
#pragma unroll
            for (int kf = 0; kf < 4; ++kf)
#pragma unroll
                for (int r = 0; r < 4; ++r) {
                    p[kf][r] = __expf(p[kf][r] - mnew);
                    rs += p[kf][r];
                }
            rs += __shfl_xor(rs, 16);
            rs += __shfl_xor(rs, 32);
            lrun[qf] = lrun[qf] * al + rs;
            // rescale O (lane-local: O col = q = l15)
#pragma unroll
            for (int dc = 0; dc < 4; ++dc)
#pragma unroll
                for (int r = 0; r < 4; ++r) o[qf][dc][r] *= al;
            // pack P -> LDS as [q][key], b64 writes, XOR-swizzled
            __hip_bfloat16* Pw = &P_lds[wid][qf][0];
#pragma unroll
            for (int kf = 0; kf < 4; ++kf) {
                uint2 w;
                w.x = pack2(p[kf][0], p[kf][1]);
                w.y = pack2(p[kf][2], p[kf][3]);
                *(uint2*)&Pw[l15 * 64 + ((kf * 16 + lg * 4) ^ swz)] = w;
            }
            // PV: O = mfma(Vt, P)
#pragma unroll
            for (int c2 = 0; c2 < 2; ++c2) {
                if (ks + c2 * 32 <= qlo + 15) {
                    const bf16x8 pb = *(const bf16x8*)&Pw[l15 * 64 + ((c2 * 32 + lg * 8) ^ swz)];
#pragma unroll
                    for (int dc = 0; dc < 4; ++dc)
                        o[qf][dc] = __builtin_amdgcn_mfma_f32_16x16x32_bf16(bv[dc][c2], pb, o[qf][dc], 0, 0, 0);
                }
            }
        }
    }

    const int bq = bh >> 4, hh = bh & 15;
#pragma unroll
    for (int qf = 0; qf < 2; ++qf) {
        const float inv = 1.0f / lrun[qf];
        const size_t rowb = ((size_t)(bq * 2048 + qw + qf * 16 + l15)) * 1024 + hh * 64;
#pragma unroll
        for (int dc = 0; dc < 4; ++dc) {
            bf16x4 st;
#pragma unroll
            for (int r = 0; r < 4; ++r)
                st[r] = (short)__bfloat16_as_ushort(__float2bfloat16(o[qf][dc][r] * inv));
            *(bf16x4*)(att + rowb + dc * 16 + lg * 4) = st;
        }
    }
}

// ---------------------------------------------------------------------------
extern "C" void kernel_launch(void* const* d_in, const int* in_sizes, int n_in,
                              void* d_out, int out_size, void* d_ws, size_t ws_size,
                              hipStream_t stream)
{
    const float* x    = (const float*)d_in[0];   // [2,2048,1024]
    const float* Wqkv = (const float*)d_in[1];   // [1024,3072]
    const float* bqkv = (const float*)d_in[2];   // [3072]
    const float* Wo   = (const float*)d_in[3];   // [1024,1024]
    const float* bo   = (const float*)d_in[4];   // [1024]
    float* out = (float*)d_out;                  // [2,2048,1024]

    char* ws = (char*)d_ws;
    const size_t MB = 1024 * 1024;
    __hip_bfloat16* xb    = (__hip_bfloat16*)(ws);            //  8 MB
    __hip_bfloat16* WqkvT = (__hip_bfloat16*)(ws + 8 * MB);   //  6 MB
    __hip_bfloat16* WoT   = (__hip_bfloat16*)(ws + 14 * MB);  //  2 MB
    __hip_bfloat16* Qb    = (__hip_bfloat16*)(ws + 16 * MB);  //  8 MB
    __hip_bfloat16* Kb    = (__hip_bfloat16*)(ws + 24 * MB);  //  8 MB
    __hip_bfloat16* Vt    = (__hip_bfloat16*)(ws + 32 * MB);  //  8 MB
    __hip_bfloat16* att   = (__hip_bfloat16*)(ws + 40 * MB);  //  8 MB

    k_f32_to_bf16<<<2048, 256, 0, stream>>>(x, xb, 4096 * 1024 / 4);
    k_transpose_f32_bf16<<<dim3(96, 32), 256, 0, stream>>>(Wqkv, WqkvT, 1024, 3072);
    k_transpose_f32_bf16<<<dim3(32, 32), 256, 0, stream>>>(Wo, WoT, 1024, 1024);

    k_gemm_bt<0><<<dim3(24, 32), 256, 0, stream>>>(
        xb, WqkvT, bqkv, 1024, 3072, nullptr, Qb, Kb, Vt);

    k_attn<<<512, 256, 0, stream>>>(Qb, Kb, Vt, att);

    k_gemm_bt<1><<<dim3(8, 32), 256, 0, stream>>>(
        att, WoT, bo, 1024, 1024, out, nullptr, nullptr, nullptr);
}